// Round 1
// baseline (556.012 us; speedup 1.0000x reference)
//
#include <hip/hip_runtime.h>

// Problem constants (match reference)
#define SEQ    256
#define BATCH  32
#define INDIM  256
#define HID    256
#define LSTMH  16
#define NT     2
#define DIM    128
#define LTAPE  256

__device__ __forceinline__ float sigm(float x) { return 1.f / (1.f + __expf(-x)); }
__device__ __forceinline__ float tanh_(float x) { float e = __expf(2.f * x); return 1.f - 2.f / (e + 1.f); }

// ---------------------------------------------------------------------------
// C[M][N] = A[M][256] @ W[N][256]^T + b1[N] (+ b2[N])
// 64x64 tile, BK=16, 4x4 per thread, 256 threads.
// ---------------------------------------------------------------------------
__global__ __launch_bounds__(256) void gemm_nt(
    const float* __restrict__ A, const float* __restrict__ W,
    const float* __restrict__ b1, const float* __restrict__ b2,
    float* __restrict__ C, int N) {
  __shared__ float As[16][68];
  __shared__ float Bs[16][68];
  const int tid = threadIdx.x;
  const int bm = blockIdx.x * 64;
  const int bn = blockIdx.y * 64;
  const int lr  = tid >> 2;        // 0..63 row within tile
  const int lc4 = (tid & 3) * 4;   // k sub-offset 0,4,8,12
  const int tm = (tid & 15) * 4;
  const int tn = (tid >> 4) * 4;
  float acc[4][4];
#pragma unroll
  for (int i = 0; i < 4; ++i)
#pragma unroll
    for (int j = 0; j < 4; ++j) acc[i][j] = 0.f;

  for (int k0 = 0; k0 < 256; k0 += 16) {
    float4 av = *reinterpret_cast<const float4*>(&A[(bm + lr) * 256 + k0 + lc4]);
    float4 bv = *reinterpret_cast<const float4*>(&W[(bn + lr) * 256 + k0 + lc4]);
    __syncthreads();
    As[lc4 + 0][lr] = av.x; As[lc4 + 1][lr] = av.y; As[lc4 + 2][lr] = av.z; As[lc4 + 3][lr] = av.w;
    Bs[lc4 + 0][lr] = bv.x; Bs[lc4 + 1][lr] = bv.y; Bs[lc4 + 2][lr] = bv.z; Bs[lc4 + 3][lr] = bv.w;
    __syncthreads();
#pragma unroll
    for (int kk = 0; kk < 16; ++kk) {
      float4 a = *reinterpret_cast<const float4*>(&As[kk][tm]);
      float4 b = *reinterpret_cast<const float4*>(&Bs[kk][tn]);
      float a_[4] = {a.x, a.y, a.z, a.w};
      float b_[4] = {b.x, b.y, b.z, b.w};
#pragma unroll
      for (int i = 0; i < 4; ++i)
#pragma unroll
        for (int j = 0; j < 4; ++j) acc[i][j] += a_[i] * b_[j];
    }
  }
#pragma unroll
  for (int i = 0; i < 4; ++i) {
#pragma unroll
    for (int j = 0; j < 4; ++j) {
      int n = bn + tn + j;
      float bias = b1[n] + (b2 ? b2[n] : 0.f);
      C[(size_t)(bm + tm + i) * N + n] = acc[i][j] + bias;
    }
  }
}

// ---------------------------------------------------------------------------
// LSTM + action heads. One wave (64 threads) per batch row; 32 blocks.
// lane = q*16 + k : gate group q in {i,f,g,o}, hidden unit k.
// Entirely shuffle-based, no LDS, no barriers.
// ---------------------------------------------------------------------------
__global__ __launch_bounds__(64) void lstm_kernel(
    const float* __restrict__ xg,    // [SEQ][BATCH][64]
    const float* __restrict__ W_hh,  // [64][16]
    float* __restrict__ dr,          // [SEQ][BATCH][NT][3]
    float* __restrict__ dw,          // [SEQ][BATCH][NT][3]
    float* __restrict__ rw) {        // [SEQ][BATCH][NT][2]
  const int b = blockIdx.x;
  const int lane = threadIdx.x;
  const int k = lane & 15;
  const int q = lane >> 4;
  float wrow[16];
#pragma unroll
  for (int kk = 0; kk < 16; ++kk) wrow[kk] = W_hh[lane * 16 + kk];

  float h = 0.f, c = 0.f;
  const int t = k >> 3, e = k & 7, t8 = t * 8;
  for (int s = 0; s < SEQ; ++s) {
    float g = xg[(size_t)(s * BATCH + b) * 64 + lane];
#pragma unroll
    for (int kk = 0; kk < 16; ++kk) g += wrow[kk] * __shfl(h, kk, 64);
    float gi = __shfl(g, k, 64);
    float gf = __shfl(g, 16 + k, 64);
    float gg = __shfl(g, 32 + k, 64);
    float go = __shfl(g, 48 + k, 64);
    c = sigm(gf) * c + sigm(gi) * tanh_(gg);
    h = sigm(go) * tanh_(c);
    // action heads (all lanes shuffle; lanes q==0 store)
    float a0 = __shfl(h, t8 + 0, 64), a1 = __shfl(h, t8 + 1, 64), a2 = __shfl(h, t8 + 2, 64);
    float a3 = __shfl(h, t8 + 3, 64), a4 = __shfl(h, t8 + 4, 64), a5 = __shfl(h, t8 + 5, 64);
    float a6 = __shfl(h, t8 + 6, 64), a7 = __shfl(h, t8 + 7, 64);
    if (q == 0) {
      const int base = (s * BATCH + b) * NT + t;
      if (e < 3) {
        float m = fmaxf(a0, fmaxf(a1, a2));
        float e0 = __expf(a0 - m), e1 = __expf(a1 - m), e2 = __expf(a2 - m);
        float inv = 1.f / (e0 + e1 + e2);
        dr[base * 3 + e] = (e == 0 ? e0 : (e == 1 ? e1 : e2)) * inv;
      } else if (e < 6) {
        float m = fmaxf(a3, fmaxf(a4, a5));
        float e0 = __expf(a3 - m), e1 = __expf(a4 - m), e2 = __expf(a5 - m);
        float inv = 1.f / (e0 + e1 + e2);
        dw[base * 3 + (e - 3)] = (e == 3 ? e0 : (e == 4 ? e1 : e2)) * inv;
      } else {
        rw[base * 2 + (e - 6)] = sigm(e == 6 ? a6 : a7);
      }
    }
  }
}

// ---------------------------------------------------------------------------
// Tape scan. Block = (pair p = b*NT+t, channel-quarter cq). 256 blocks x 256 thr.
// Thread (c32 = tid&31, lh = tid>>5) owns tape[lh*32 .. lh*32+31][c] in regs.
// Positions double-buffered in LDS; l-reduction: shfl_xor(32) + 4-wave LDS sum.
// ---------------------------------------------------------------------------
__global__ __launch_bounds__(256) void tape_kernel(
    const float* __restrict__ values,  // [SEQ][BATCH][NT][DIM]
    const float* __restrict__ dr, const float* __restrict__ dw,
    const float* __restrict__ rwp,     // [SEQ][BATCH][NT][2]
    float* __restrict__ reads,         // [SEQ][BATCH][NT][DIM]
    float* __restrict__ out_tape,      // [LTAPE][BATCH][NT][DIM]
    float* __restrict__ out_rpos,      // [LTAPE][BATCH][NT]
    float* __restrict__ out_wpos) {
  const int blk = blockIdx.x;
  const int p = blk >> 2, cq = blk & 3;
  const int b = p >> 1, t = p & 1;
  const int tid = threadIdx.x;
  const int c32 = tid & 31, lh = tid >> 5;
  const int c = cq * 32 + c32;
  const int wv = tid >> 6;

  __shared__ float Rp[2][LTAPE];
  __shared__ float Wp[2][LTAPE];
  __shared__ float redA[4][32];
  __shared__ float redB[4][32];

  Rp[0][tid] = (tid == 0) ? 1.f : 0.f;
  Wp[0][tid] = (tid == 0) ? 1.f : 0.f;
  float tp[32];
#pragma unroll
  for (int i = 0; i < 32; ++i) tp[i] = 0.f;
  __syncthreads();

  int cur = 0;
  for (int s = 0; s < SEQ; ++s) {
    const int pb = (s * BATCH + b) * NT + t;
    const float rd0 = dr[pb * 3 + 0], rd1 = dr[pb * 3 + 1], rd2 = dr[pb * 3 + 2];
    const float wd0 = dw[pb * 3 + 0], wd1 = dw[pb * 3 + 1], wd2 = dw[pb * 3 + 2];
    const float rw0 = rwp[pb * 2 + 0], rw1 = rwp[pb * 2 + 1];
    const float v = values[(size_t)pb * DIM + c];

    // pass A: oldval partial (dot of tape column with wpos)
    float wl[32];
    float pA = 0.f;
#pragma unroll
    for (int i = 0; i < 32; ++i) {
      wl[i] = Wp[cur][lh * 32 + i];
      pA += tp[i] * wl[i];
    }
    pA += __shfl_xor(pA, 32, 64);
    if ((tid & 63) < 32) redA[wv][c32] = pA;
    __syncthreads();
    const float oldval = redA[0][c32] + redA[1][c32] + redA[2][c32] + redA[3][c32];
    const float delta = (v - oldval) * rw1;

    // pass B: rank-1 update + read partial
    float qv = 0.f;
#pragma unroll
    for (int i = 0; i < 32; ++i) {
      tp[i] += wl[i] * delta;
      qv += tp[i] * Rp[cur][lh * 32 + i];
    }
    qv += __shfl_xor(qv, 32, 64);
    if ((tid & 63) < 32) redB[wv][c32] = qv;

    // position update (reads cur, writes nxt)
    const int nxt = cur ^ 1;
    {
      const int l = tid;
      const float r_m = Rp[cur][(l + 255) & 255];
      const float r_0 = Rp[cur][l];
      const float r_p = Rp[cur][(l + 1) & 255];
      const float w_0 = Wp[cur][l];
      Wp[nxt][l] = r_p * wd0 + w_0 * wd1 + r_m * wd2;
      Rp[nxt][l] = r_p * rd0 + r_0 * rd1 + r_m * rd2;
    }
    __syncthreads();
    const float rsum = (redB[0][c32] + redB[1][c32] + redB[2][c32] + redB[3][c32]) * rw0;
    if (lh == 0) reads[(size_t)pb * DIM + c] = rsum;
    cur = nxt;
  }

  // final tape
#pragma unroll
  for (int i = 0; i < 32; ++i) {
    const int l = lh * 32 + i;
    out_tape[(size_t)((l * BATCH + b) * NT + t) * DIM + c] = tp[i];
  }
  // final positions (post last update), one channel-quarter writes
  if (cq == 0) {
    out_rpos[(tid * BATCH + b) * NT + t] = Rp[cur][tid];
    out_wpos[(tid * BATCH + b) * NT + t] = Wp[cur][tid];
  }
}

// ---------------------------------------------------------------------------
extern "C" void kernel_launch(void* const* d_in, const int* in_sizes, int n_in,
                              void* d_out, int out_size, void* d_ws, size_t ws_size,
                              hipStream_t stream) {
  const float* inputs = (const float*)d_in[0];
  // d_in[1] = tapelen (==256, hardcoded)
  const float* W_ih = (const float*)d_in[2];
  const float* W_hh = (const float*)d_in[3];
  const float* b_ih = (const float*)d_in[4];
  const float* b_hh = (const float*)d_in[5];
  const float* W_val = (const float*)d_in[6];
  const float* b_val = (const float*)d_in[7];
  const float* W_out = (const float*)d_in[8];
  const float* b_out = (const float*)d_in[9];

  float* out = (float*)d_out;
  float* out_tape = out + 2097152;   // SEQ*BATCH*HID
  float* out_rpos = out + 4194304;
  float* out_wpos = out + 4210688;

  float* ws = (float*)d_ws;
  float* values = ws;                // 2,097,152
  float* xg     = ws + 2097152;      //   524,288
  float* drr    = ws + 2621440;      //    49,152
  float* dww    = ws + 2670592;      //    49,152
  float* rwp    = ws + 2719744;      //    32,768
  float* reads  = ws + 2752512;      // 2,097,152

  // values = inputs @ W_val^T + b_val
  gemm_nt<<<dim3(128, 4), 256, 0, stream>>>(inputs, W_val, b_val, nullptr, values, 256);
  // xg = inputs @ W_ih^T + (b_ih + b_hh)
  gemm_nt<<<dim3(128, 1), 256, 0, stream>>>(inputs, W_ih, b_ih, b_hh, xg, 64);
  // LSTM -> direction/probability coefficients
  lstm_kernel<<<32, 64, 0, stream>>>(xg, W_hh, drr, dww, rwp);
  // tape scan -> reads, final tape, final positions
  tape_kernel<<<256, 256, 0, stream>>>(values, drr, dww, rwp, reads, out_tape, out_rpos, out_wpos);
  // outputs = reads @ W_out^T + b_out
  gemm_nt<<<dim3(128, 4), 256, 0, stream>>>(reads, W_out, b_out, nullptr, out, 256);
}